// Round 4
// baseline (221.131 us; speedup 1.0000x reference)
//
#include <hip/hip_runtime.h>

#define BB 32
#define FF 8
#define NN 131072
#define CC 16

#define NBLK 1024
#define CPB  32            // chunks (blocks) per batch
#define PTS  4096          // points per block chunk

constexpr float DELTA_VAR  = 0.5f;
constexpr float DELTA_DIST = 1.5f;
constexpr float ALPHA = 1.0f, BETA = 1.0f, GAMMA = 0.001f;

// ws layout. ints (counters) live in float-slots [0,33); floats after.
// Zero region: [0, 4673) floats = 18692 bytes (counters + sums + counts + var).
#define WS_SUMS  64        // 4096: b*128 + f*16 + c   (atomic accum)
#define WS_CNTF  4160      // 512:  b*16 + c           (atomic accum)
#define WS_VAR   4672      // 1                        (atomic accum)
#define WS_MEANS 4736      // 4096: (b*16+c)*8 + f     (16B aligned)
#define WS_INV   8832      // 512
#define WS_DRG   9344      // 32

// ---------------- Kernel A: sums + counts, last block per batch does "mid" ---
__global__ __launch_bounds__(256) void k_sums(const float* __restrict__ x,
                                              const int* __restrict__ tgt,
                                              float* __restrict__ ws,
                                              int* __restrict__ wsi) {
    __shared__ float priv[256 * 17];   // private rows, stride 17 (~2-way, free)
    __shared__ float cpriv[32 * 17];   // counts (f==0 group)
    __shared__ float red2[144];
    __shared__ float smeanA[CC * FF];
    __shared__ int   st[CC];
    __shared__ int   lastflag;

    const int tid = threadIdx.x;
    const int blk = blockIdx.x;
    const int b   = blk >> 5;
    const int n0  = (blk & 31) * PTS;

#pragma unroll
    for (int i = 0; i < 16; ++i) priv[tid * 17 + i] = 0.f;
    if (tid < 32) {
#pragma unroll
        for (int i = 0; i < 16; ++i) cpriv[tid * 17 + i] = 0.f;
    }
    __syncthreads();

    {
        const int f = tid >> 5;        // feature group 0..7
        const int g = tid & 31;
        const float* __restrict__ xf = x + (size_t)b * FF * NN + (size_t)f * NN;
        const int*   __restrict__ tb = tgt + (size_t)b * NN;
        const int base  = tid * 17;
        const int cbase = g * 17;
#pragma unroll 2
        for (int k = 0; k < PTS / 128; ++k) {
            const int n = n0 + k * 128 + g * 4;
            const int4   t4 = *reinterpret_cast<const int4*>(tb + n);
            const float4 v  = *reinterpret_cast<const float4*>(xf + n);
            priv[base + t4.x] += v.x;
            priv[base + t4.y] += v.y;
            priv[base + t4.z] += v.z;
            priv[base + t4.w] += v.w;
            if (f == 0) {
                cpriv[cbase + t4.x] += 1.f;
                cpriv[cbase + t4.y] += 1.f;
                cpriv[cbase + t4.z] += 1.f;
                cpriv[cbase + t4.w] += 1.f;
            }
        }
    }
    __syncthreads();

    if (tid < 128) {
        const int rf = tid >> 4, rc = tid & 15;
        float s = 0.f;
#pragma unroll
        for (int g = 0; g < 32; ++g) s += priv[(rf * 32 + g) * 17 + rc];
        atomicAdd(&ws[WS_SUMS + b * 128 + rf * 16 + rc], s);
    } else if (tid < 144) {
        const int rc = tid - 128;
        float s = 0.f;
#pragma unroll
        for (int g = 0; g < 32; ++g) s += cpriv[g * 17 + rc];
        atomicAdd(&ws[WS_CNTF + b * 16 + rc], s);
    }
    __threadfence();               // make this block's atomics device-visible
    __syncthreads();
    if (tid == 0) lastflag = (atomicAdd(&wsi[b], 1) == CPB - 1);
    __syncthreads();
    if (!lastflag) return;

    // ---- mid (only the 32nd block of batch b runs this) ----
    if (tid < 128)       red2[tid] = ws[WS_SUMS + b * 128 + tid];
    else if (tid < 144)  red2[tid] = ws[WS_CNTF + b * 16 + (tid - 128)];
    if (tid < CC) st[tid] = tgt[(size_t)b * NN + tid];
    __syncthreads();

    float l1 = 0.f;
    if (tid < CC) {
        const int c = tid;
        const float cnt = red2[128 + c];
        const float inv = cnt > 0.f ? 1.f / cnt : 0.f;
        ws[WS_INV + b * CC + c] = inv;
#pragma unroll
        for (int f = 0; f < FF; ++f) {
            const float m = red2[f * 16 + c] * inv;
            smeanA[c * FF + f] = m;
            ws[WS_MEANS + (b * CC + c) * FF + f] = m;
            l1 += fabsf(m);
        }
    }
    __syncthreads();

    float contrib = 0.f;
    if (tid < CC) {
        const int ti = st[tid];
        float mi[FF];
#pragma unroll
        for (int f = 0; f < FF; ++f) mi[f] = smeanA[ti * FF + f];
        float dsum = 0.f;
        for (int j = 0; j < CC; ++j) {
            const int tj = st[j];
            float d = 0.f;
#pragma unroll
            for (int f = 0; f < FF; ++f) d += fabsf(mi[f] - smeanA[tj * FF + f]);
            if (j != tid) {
                const float h = 2.f * DELTA_DIST - d;
                if (h > 0.f) dsum += h * h;
            }
        }
        contrib = (GAMMA / (float)(CC * BB)) * l1
                + (BETA / (float)(CC * (CC - 1) * BB)) * dsum;
    }
    // lanes 0..15 hold values, rest zero; reduce within wave 0
#pragma unroll
    for (int off = 8; off > 0; off >>= 1) contrib += __shfl_down(contrib, off, 64);
    if (tid == 0) ws[WS_DRG + b] = contrib;
}

// ---------------- Kernel B: var pass, last block of grid does final ----------
__global__ __launch_bounds__(256) void k_var(const float* __restrict__ x,
                                             const int* __restrict__ tgt,
                                             float* __restrict__ ws,
                                             int* __restrict__ wsi,
                                             float* __restrict__ out) {
    __shared__ float4 sm4[CC * 2];     // means, [c*8+f] as float4 pairs
    __shared__ float  sinv[CC];
    __shared__ float  red[4];
    __shared__ int    lastflag;

    const int tid = threadIdx.x;
    const int blk = blockIdx.x;
    const int b   = blk >> 5;
    const int n0  = (blk & 31) * PTS;

    if (tid < 32) sm4[tid] = reinterpret_cast<const float4*>(&ws[WS_MEANS + b * 128])[tid];
    else if (tid >= 64 && tid < 80) sinv[tid - 64] = ws[WS_INV + b * CC + (tid - 64)];
    __syncthreads();

    const float* __restrict__ xb = x + (size_t)b * FF * NN;
    const int*   __restrict__ tb = tgt + (size_t)b * NN;

    float acc = 0.f;
#pragma unroll 2
    for (int n = n0 + tid * 4; n < n0 + PTS; n += 1024) {
        const int4 t4 = *reinterpret_cast<const int4*>(tb + n);
        const float4 A0 = sm4[2 * t4.x], B0 = sm4[2 * t4.x + 1];
        const float4 A1 = sm4[2 * t4.y], B1 = sm4[2 * t4.y + 1];
        const float4 A2 = sm4[2 * t4.z], B2 = sm4[2 * t4.z + 1];
        const float4 A3 = sm4[2 * t4.w], B3 = sm4[2 * t4.w + 1];
        float s0, s1, s2, s3;
        {
            const float4 v = *reinterpret_cast<const float4*>(xb + 0 * NN + n);
            s0 = fabsf(v.x - A0.x); s1 = fabsf(v.y - A1.x);
            s2 = fabsf(v.z - A2.x); s3 = fabsf(v.w - A3.x);
        }
        {
            const float4 v = *reinterpret_cast<const float4*>(xb + 1 * NN + n);
            s0 += fabsf(v.x - A0.y); s1 += fabsf(v.y - A1.y);
            s2 += fabsf(v.z - A2.y); s3 += fabsf(v.w - A3.y);
        }
        {
            const float4 v = *reinterpret_cast<const float4*>(xb + 2 * NN + n);
            s0 += fabsf(v.x - A0.z); s1 += fabsf(v.y - A1.z);
            s2 += fabsf(v.z - A2.z); s3 += fabsf(v.w - A3.z);
        }
        {
            const float4 v = *reinterpret_cast<const float4*>(xb + 3 * NN + n);
            s0 += fabsf(v.x - A0.w); s1 += fabsf(v.y - A1.w);
            s2 += fabsf(v.z - A2.w); s3 += fabsf(v.w - A3.w);
        }
        {
            const float4 v = *reinterpret_cast<const float4*>(xb + 4 * NN + n);
            s0 += fabsf(v.x - B0.x); s1 += fabsf(v.y - B1.x);
            s2 += fabsf(v.z - B2.x); s3 += fabsf(v.w - B3.x);
        }
        {
            const float4 v = *reinterpret_cast<const float4*>(xb + 5 * NN + n);
            s0 += fabsf(v.x - B0.y); s1 += fabsf(v.y - B1.y);
            s2 += fabsf(v.z - B2.y); s3 += fabsf(v.w - B3.y);
        }
        {
            const float4 v = *reinterpret_cast<const float4*>(xb + 6 * NN + n);
            s0 += fabsf(v.x - B0.z); s1 += fabsf(v.y - B1.z);
            s2 += fabsf(v.z - B2.z); s3 += fabsf(v.w - B3.z);
        }
        {
            const float4 v = *reinterpret_cast<const float4*>(xb + 7 * NN + n);
            s0 += fabsf(v.x - B0.w); s1 += fabsf(v.y - B1.w);
            s2 += fabsf(v.z - B2.w); s3 += fabsf(v.w - B3.w);
        }
        float h;
        h = fmaxf(s0 - DELTA_VAR, 0.f); acc += h * h * sinv[t4.x];
        h = fmaxf(s1 - DELTA_VAR, 0.f); acc += h * h * sinv[t4.y];
        h = fmaxf(s2 - DELTA_VAR, 0.f); acc += h * h * sinv[t4.z];
        h = fmaxf(s3 - DELTA_VAR, 0.f); acc += h * h * sinv[t4.w];
    }

#pragma unroll
    for (int off = 32; off > 0; off >>= 1) acc += __shfl_down(acc, off, 64);
    if ((tid & 63) == 0) red[tid >> 6] = acc;
    __syncthreads();
    if (tid == 0) atomicAdd(&ws[WS_VAR], red[0] + red[1] + red[2] + red[3]);
    __threadfence();
    __syncthreads();
    if (tid == 0) lastflag = (atomicAdd(&wsi[32], 1) == NBLK - 1);
    __syncthreads();
    if (!lastflag) return;

    if (tid == 0) {
        float drg = 0.f;
#pragma unroll
        for (int i = 0; i < BB; ++i) drg += ws[WS_DRG + i];
        out[0] = ALPHA * ws[WS_VAR] / (float)BB + drg;
    }
}

extern "C" void kernel_launch(void* const* d_in, const int* in_sizes, int n_in,
                              void* d_out, int out_size, void* d_ws, size_t ws_size,
                              hipStream_t stream) {
    const float* x  = (const float*)d_in[0];
    const int* tgt  = (const int*)d_in[1];
    float* out = (float*)d_out;
    float* ws  = (float*)d_ws;
    int*   wsi = (int*)d_ws;

    // zero counters + atomic accumulators: floats [0, 4673)
    hipMemsetAsync(ws, 0, (size_t)4673 * sizeof(float), stream);

    k_sums<<<NBLK, 256, 0, stream>>>(x, tgt, ws, wsi);
    k_var <<<NBLK, 256, 0, stream>>>(x, tgt, ws, wsi, out);
}